// Round 4
// baseline (630.655 us; speedup 1.0000x reference)
//
#include <hip/hip_runtime.h>

#define D 128            // feature dim
#define K2 256           // concat dim

typedef float vfloat4 __attribute__((ext_vector_type(4)));

// ---------------- CSR build ----------------

__global__ void hist_kernel(const int* __restrict__ idx, int* __restrict__ cnt, int n) {
    int e = blockIdx.x * 256 + threadIdx.x;
    if (e < n) atomicAdd(&cnt[idx[e]], 1);
}

// single block, 1024 threads: full exclusive scan of cnt[0..n) -> off, cur; off[n]=total.
__global__ __launch_bounds__(1024) void scan_all_kernel(const int* __restrict__ cnt,
                                                        int* __restrict__ off,
                                                        int* __restrict__ cur, int n) {
    __shared__ int s[1024];
    const int t = threadIdx.x;
    const int chunk = (n + 1023) / 1024;
    int b = t * chunk;
    int e = b + chunk;
    if (b > n) b = n;
    if (e > n) e = n;
    int sum = 0;
    for (int i = b; i < e; ++i) sum += cnt[i];
    s[t] = sum;
    __syncthreads();
    int v = sum;
    for (int d = 1; d < 1024; d <<= 1) {
        int u = (t >= d) ? s[t - d] : 0;
        __syncthreads();
        s[t] += u;
        __syncthreads();
    }
    int run = s[t] - v;  // exclusive prefix of this thread's chunk
    for (int i = b; i < e; ++i) {
        off[i] = run;
        cur[i] = run;
        run += cnt[i];
    }
    if (t == 1023) off[n] = s[1023];
}

__global__ void scatter_kernel(const int* __restrict__ idx, int* __restrict__ cur,
                               int* __restrict__ eid, int n) {
    int e = blockIdx.x * 256 + threadIdx.x;
    if (e < n) {
        int p = atomicAdd(&cur[idx[e]], 1);
        eid[p] = e;
    }
}

// ---------------- aggregate: one wave per node, 2 rows across wave-halves ----------------
// lanes 0-31 = row j+0, lanes 32-63 = row j+1; float4/lane = 512 B/row.
// 16-row main step keeps 8 x 512B gathers in flight per wave.

__global__ __launch_bounds__(64) void aggregate_kernel(const float* __restrict__ nbr,
                                                       const int* __restrict__ eid,
                                                       const int* __restrict__ off,
                                                       float* __restrict__ agg) {
    const int node = blockIdx.x;
    const int beg = off[node], end = off[node + 1];
    const int t = threadIdx.x;
    const int h = t >> 5;       // which row of the pair
    const int l = t & 31;       // float4 index within the row
    const vfloat4* __restrict__ rows = (const vfloat4*)nbr;
    vfloat4 acc = {0.f, 0.f, 0.f, 0.f};
    int j = beg;
    for (; j + 16 <= end; j += 16) {
        int e0 = eid[j + 0 + h], e1 = eid[j + 2 + h], e2 = eid[j + 4 + h], e3 = eid[j + 6 + h];
        int e4 = eid[j + 8 + h], e5 = eid[j + 10 + h], e6 = eid[j + 12 + h], e7 = eid[j + 14 + h];
        vfloat4 v0 = __builtin_nontemporal_load(rows + (size_t)e0 * 32 + l);
        vfloat4 v1 = __builtin_nontemporal_load(rows + (size_t)e1 * 32 + l);
        vfloat4 v2 = __builtin_nontemporal_load(rows + (size_t)e2 * 32 + l);
        vfloat4 v3 = __builtin_nontemporal_load(rows + (size_t)e3 * 32 + l);
        vfloat4 v4 = __builtin_nontemporal_load(rows + (size_t)e4 * 32 + l);
        vfloat4 v5 = __builtin_nontemporal_load(rows + (size_t)e5 * 32 + l);
        vfloat4 v6 = __builtin_nontemporal_load(rows + (size_t)e6 * 32 + l);
        vfloat4 v7 = __builtin_nontemporal_load(rows + (size_t)e7 * 32 + l);
        acc += ((v0 + v1) + (v2 + v3)) + ((v4 + v5) + (v6 + v7));
    }
    if (j + 8 <= end) {
        int e0 = eid[j + 0 + h], e1 = eid[j + 2 + h], e2 = eid[j + 4 + h], e3 = eid[j + 6 + h];
        vfloat4 v0 = __builtin_nontemporal_load(rows + (size_t)e0 * 32 + l);
        vfloat4 v1 = __builtin_nontemporal_load(rows + (size_t)e1 * 32 + l);
        vfloat4 v2 = __builtin_nontemporal_load(rows + (size_t)e2 * 32 + l);
        vfloat4 v3 = __builtin_nontemporal_load(rows + (size_t)e3 * 32 + l);
        acc += (v0 + v1) + (v2 + v3);
        j += 8;
    }
    if (j + 4 <= end) {
        int e0 = eid[j + 0 + h], e1 = eid[j + 2 + h];
        vfloat4 v0 = __builtin_nontemporal_load(rows + (size_t)e0 * 32 + l);
        vfloat4 v1 = __builtin_nontemporal_load(rows + (size_t)e1 * 32 + l);
        acc += v0 + v1;
        j += 4;
    }
    for (; j < end; j += 2) {
        int jj = j + h;
        if (jj < end) {
            int e = eid[jj];
            acc += __builtin_nontemporal_load(rows + (size_t)e * 32 + l);
        }
    }
    acc.x += __shfl_xor(acc.x, 32);
    acc.y += __shfl_xor(acc.y, 32);
    acc.z += __shfl_xor(acc.z, 32);
    acc.w += __shfl_xor(acc.w, 32);
    int c = end - beg;
    float inv = (c > 0) ? 1.0f / (float)c : 0.0f;
    if (h == 0) {
        vfloat4 o = acc * inv;
        *((vfloat4*)agg + (size_t)node * 32 + l) = o;
    }
}

// ---------------- fused concat-matmul: out = [self | agg] @ W ----------------
// 64 rows x 128 cols per block, 128 threads, 8x8 f32 accumulators per thread.

#define MT 64
#define KB 32
#define XP (MT + 4)   // pad: staging writes spread banks; b128 reads stay 16B-aligned

__global__ __launch_bounds__(128) void matmul_kernel(const float* __restrict__ self,
                                                     const float* __restrict__ agg,
                                                     const float* __restrict__ W,
                                                     float* __restrict__ out, int nNodes) {
    __shared__ float Xs[KB][XP];    // transposed: Xs[k][m]
    __shared__ float Ws[KB][D];     // Ws[k][n]
    const int t = threadIdx.x;
    const int m_base = blockIdx.x * MT;
    const int n0 = (t & 15) * 8;    // 16 col groups
    const int m0 = (t >> 4) * 8;    // 8 row groups

    float acc[8][8];
#pragma unroll
    for (int i = 0; i < 8; ++i)
#pragma unroll
        for (int j = 0; j < 8; ++j) acc[i][j] = 0.f;

    for (int k0 = 0; k0 < K2; k0 += KB) {
        const float* src = (k0 < D) ? self : agg;
        const int koff = k0 & (D - 1);
#pragma unroll
        for (int it = 0; it < 4; ++it) {
            int lin = t + it * 128;          // float4 index; 8 float4 per row
            int row = lin >> 3;
            int k4 = lin & 7;
            int gr = m_base + row;
            if (gr >= nNodes) gr = nNodes - 1;
            float4 v = *(const float4*)(src + (size_t)gr * D + koff + k4 * 4);
            Xs[k4 * 4 + 0][row] = v.x;
            Xs[k4 * 4 + 1][row] = v.y;
            Xs[k4 * 4 + 2][row] = v.z;
            Xs[k4 * 4 + 3][row] = v.w;
        }
#pragma unroll
        for (int it = 0; it < 8; ++it) {
            int lin = t + it * 128;          // 32 float4 per k-row
            int kk = lin >> 5;
            int n4 = lin & 31;
            *(float4*)(&Ws[kk][n4 * 4]) = *(const float4*)(W + (size_t)(k0 + kk) * D + n4 * 4);
        }
        __syncthreads();

#pragma unroll
        for (int kk4 = 0; kk4 < KB / 4; ++kk4) {
            float4 xa[4], xb[4], wa[4], wb[4];
#pragma unroll
            for (int kq = 0; kq < 4; ++kq) {
                int k = kk4 * 4 + kq;
                xa[kq] = *(const float4*)(&Xs[k][m0]);
                xb[kq] = *(const float4*)(&Xs[k][m0 + 4]);
                wa[kq] = *(const float4*)(&Ws[k][n0]);
                wb[kq] = *(const float4*)(&Ws[k][n0 + 4]);
            }
#pragma unroll
            for (int kq = 0; kq < 4; ++kq) {
                const float xr[8] = {xa[kq].x, xa[kq].y, xa[kq].z, xa[kq].w,
                                     xb[kq].x, xb[kq].y, xb[kq].z, xb[kq].w};
                const float wr[8] = {wa[kq].x, wa[kq].y, wa[kq].z, wa[kq].w,
                                     wb[kq].x, wb[kq].y, wb[kq].z, wb[kq].w};
#pragma unroll
                for (int i = 0; i < 8; ++i)
#pragma unroll
                    for (int j = 0; j < 8; ++j) acc[i][j] += xr[i] * wr[j];
            }
        }
        __syncthreads();
    }

#pragma unroll
    for (int i = 0; i < 8; ++i) {
        int gr = m_base + m0 + i;
        if (gr < nNodes) {
            vfloat4 o0 = {acc[i][0], acc[i][1], acc[i][2], acc[i][3]};
            vfloat4 o1 = {acc[i][4], acc[i][5], acc[i][6], acc[i][7]};
            __builtin_nontemporal_store(o0, (vfloat4*)(out + (size_t)gr * D + n0));
            __builtin_nontemporal_store(o1, (vfloat4*)(out + (size_t)gr * D + n0 + 4));
        }
    }
}

// ---------------- launch ----------------

extern "C" void kernel_launch(void* const* d_in, const int* in_sizes, int n_in,
                              void* d_out, int out_size, void* d_ws, size_t ws_size,
                              hipStream_t stream) {
    const float* self = (const float*)d_in[0];
    const float* nbr = (const float*)d_in[1];
    const int* idx = (const int*)d_in[2];
    const float* W = (const float*)d_in[3];
    float* out = (float*)d_out;

    const int nNodes = in_sizes[0] / D;   // 50000
    const int nEdges = in_sizes[2];       // 600000

    int* cnt = (int*)d_ws;                // nNodes
    int* off = cnt + nNodes;              // nNodes+1
    int* cur = off + (nNodes + 1);        // nNodes
    int* eid = cur + nNodes;              // nEdges

    (void)hipMemsetAsync(cnt, 0, (size_t)nNodes * sizeof(int), stream);
    hist_kernel<<<(nEdges + 255) / 256, 256, 0, stream>>>(idx, cnt, nEdges);
    scan_all_kernel<<<1, 1024, 0, stream>>>(cnt, off, cur, nNodes);
    scatter_kernel<<<(nEdges + 255) / 256, 256, 0, stream>>>(idx, cur, eid, nEdges);

    // agg staged in d_out (exactly nNodes*D floats); matmul reads its own rows
    // strictly before writing them.
    aggregate_kernel<<<nNodes, 64, 0, stream>>>(nbr, eid, off, out);
    matmul_kernel<<<(nNodes + MT - 1) / MT, 128, 0, stream>>>(self, out, W, out, nNodes);
}